// Round 11
// baseline (702.448 us; speedup 1.0000x reference)
//
#include <hip/hip_runtime.h>
#include <hip/hip_bf16.h>
#include <math.h>

// Problem constants
#define NBATCH 4
#define TQD 4096
#define TBD 2048
#define CDIM 512
#define NH 8
#define HD 64
#define NINNER 2048

using short8 = __attribute__((ext_vector_type(8))) short;
using f32x4  = __attribute__((ext_vector_type(4))) float;

__device__ __forceinline__ float b2f(short s) {
  return __uint_as_float(((unsigned)(unsigned short)s) << 16);
}
__device__ __forceinline__ short f2b(float f) {
  unsigned u = __float_as_uint(f);
  return (short)((u + 0x7FFFu + ((u >> 16) & 1u)) >> 16);
}
__device__ __forceinline__ unsigned pk2(float a, float b) {
  float2 t; t.x = a; t.y = b;
  __hip_bfloat162 h = __float22bfloat162_rn(t);
  return *(unsigned*)&h;
}
__device__ __forceinline__ float gelu_fast(float x) {
  float x3 = x * x * x;
  float y2 = 1.5957691216f * (x + 0.044715f * x3);
  float e = __expf(y2);
  return x * e / (e + 1.0f);
}
__device__ __forceinline__ void gload16(const short* g, short* l) {
  __builtin_amdgcn_global_load_lds((const __attribute__((address_space(1))) void*)g,
                                   (__attribute__((address_space(3))) void*)l, 16, 0, 0);
}

// ---------------- LayerNorm (fp32 in -> bf16 out), wave-per-row, 4 rows/block
__launch_bounds__(256)
__global__ void ln_kernel(const float* __restrict__ x, const float* __restrict__ g,
                          const float* __restrict__ b, short* __restrict__ out)
{
  int row = blockIdx.x * 4 + (threadIdx.x >> 6);
  int lane = threadIdx.x & 63;
  const float4* xp = (const float4*)(x + (size_t)row * CDIM);
  float4 v0 = xp[lane], v1 = xp[lane + 64];
  float s  = v0.x + v0.y + v0.z + v0.w + v1.x + v1.y + v1.z + v1.w;
  float s2 = v0.x * v0.x + v0.y * v0.y + v0.z * v0.z + v0.w * v0.w
           + v1.x * v1.x + v1.y * v1.y + v1.z * v1.z + v1.w * v1.w;
#pragma unroll
  for (int m = 1; m < 64; m <<= 1) { s += __shfl_xor(s, m); s2 += __shfl_xor(s2, m); }
  float mean = s * (1.0f / CDIM);
  float var  = s2 * (1.0f / CDIM) - mean * mean;
  float inv  = rsqrtf(var + 1e-5f);
  float4 g0 = ((const float4*)g)[lane], g1 = ((const float4*)g)[lane + 64];
  float4 b0 = ((const float4*)b)[lane], b1 = ((const float4*)b)[lane + 64];
  uint2 o0, o1;
  o0.x = pk2((v0.x - mean) * inv * g0.x + b0.x, (v0.y - mean) * inv * g0.y + b0.y);
  o0.y = pk2((v0.z - mean) * inv * g0.z + b0.z, (v0.w - mean) * inv * g0.w + b0.w);
  o1.x = pk2((v1.x - mean) * inv * g1.x + b1.x, (v1.y - mean) * inv * g1.y + b1.y);
  o1.y = pk2((v1.z - mean) * inv * g1.z + b1.z, (v1.w - mean) * inv * g1.w + b1.w);
  uint2* op = (uint2*)(out + (size_t)row * CDIM);
  op[lane] = o0;
  op[lane + 64] = o1;
}

// ---------------- batched transpose+convert: W[K][N] f32 -> Wt[N][K] bf16
struct TcvtDesc {
  const float* src[14];
  short* dst[14];
  int K[14], N[14], nblk[14];
};
__launch_bounds__(256)
__global__ void tcvt_all(TcvtDesc d)
{
  int blk = blockIdx.x, wi = 0;
  while (blk >= d.nblk[wi]) { blk -= d.nblk[wi]; wi++; }
  const float* __restrict__ W = d.src[wi];
  short* __restrict__ Wt = d.dst[wi];
  int K = d.K[wi], N = d.N[wi];
  __shared__ float t[32][33];
  int nbk = K >> 5;
  int bk = blk % nbk, bn = blk / nbk;
  int cx = threadIdx.x & 31, cy = threadIdx.x >> 5;
#pragma unroll
  for (int i = 0; i < 4; i++)
    t[cy + 8 * i][cx] = W[(size_t)(bk * 32 + cy + 8 * i) * N + bn * 32 + cx];
  __syncthreads();
#pragma unroll
  for (int i = 0; i < 4; i++)
    Wt[(size_t)(bn * 32 + cy + 8 * i) * K + bk * 32 + cx] = f2b(t[cx][cy + 8 * i]);
}

#define VMW(n) asm volatile("s_waitcnt vmcnt(" #n ")" ::: "memory");

// ======== 128 x (NF*64) GEMM, BK=32, B DIRECT-TO-REGS (L2), A via LDS =======
// B (weights, L2-resident) is loaded per-wave straight into registers
// (double-buffered bA/bB), bypassing LDS entirely: no B publish hazard, no B
// swizzle, ~45% less LDS traffic, ONE barrier per K-tile. A stays quad-buf
// LDS [4][128][32] (gload_lds, swizzle slot^((row>>1)&3), r4-proven).
// Per tile t (steady; in-flight ledger in {}):
//   enter: {B(t)[NF], A(t+1)[1]}
//   RDA(t,q0); LDB(t+1->Y)[+NF]; STGA(t+2)[+1]  -> {2NF+2}
//   VMW(NF+1): completes B(t)+A(t+1); keeps B(t+1)+A(t+2)
//   BARRIER (A(t+1) published; all waves past their VMW)  [sched 0x0E:
//     VALU/SALU/MFMA may cross; VMEM+DS pinned so ledger is deterministic]
//   MFMAQ(0,X); RDA(t,q1); MFMAQ(1,X)
// WAR: Y regs last read tile t-1 (in-order wave => safe); A buf (t+2)&3 last
// ds_read in tile t-2, completed (lgkm) before t-1's barrier; write issues
// after it. Peel: tile NT-2 no STGA, VMW(NF); tile NT-1 VMW(0), no barrier.
// EPI: 0 = bf16 + softmax per 64-col head chunk where col<smLimit (NF=2:
// cross-wave-pair LDS exchange) + fused k-colsum when ksumP!=null
// (cols [csBase,csBase+512)); 1 = gelu bf16; 2 = residual-add fp32.
template<int EPI, int NF, int KK>
__launch_bounds__(512, 4)
__global__ void gemm128(const short* __restrict__ A, const short* __restrict__ Bt,
                        const float* __restrict__ bias, const float* __restrict__ resid,
                        void* __restrict__ outp, int M, int N, int smLimit,
                        float* __restrict__ ksumP, int csBase, int Trows)
{
  constexpr int NT = KK >> 5;
  __shared__ short As[4 * 4096];            // 4 bufs x [128][32]
  int tid = threadIdx.x, lane = tid & 63, wave = tid >> 6;
  int l15 = lane & 15, g = lane >> 4;
  int wr = wave >> 2, wn = wave & 3;
  int nbn = N / (NF * 64);
  int per = gridDim.x >> 3;
  int wg = (blockIdx.x & 7) * per + (blockIdx.x >> 3);
  int bm = wg / nbn, bn = wg % nbn;
  f32x4 acc[4][NF] = {};

  int srcslot = ((lane & 3) ^ ((lane >> 3) & 3)) * 8;
  const short* gA0 = A + (size_t)(bm * 128 + wave * 16 + (lane >> 2)) * KK + srcslot;
  short* lA = As + wave * 512;
  int rsw = (g ^ ((l15 >> 1) & 3)) * 8;
  const short* raB = As + (wr * 64 + l15) * 32 + rsw;

  // B direct: fragment n covers rows n*16+l15, k-slice g*8..+8 (operand-0
  // layout of 16x16x32: row=lane&15, k=8*(lane>>4)+i — same elements the LDS
  // path delivered, loaded straight from L2).
  const short* gB[NF];
#pragma unroll
  for (int n = 0; n < NF; n++)
    gB[n] = Bt + (size_t)(bn * (NF * 64) + wn * (NF * 16) + n * 16 + l15) * KK + g * 8;

  short8 af[2], bA[NF], bB[NF];

#define STGA1(T) gload16(gA0 + (size_t)(T) * 32, lA + ((T) & 3) * 4096);
#define LDB(T, Y) { _Pragma("unroll") for (int n = 0; n < NF; n++) \
    Y[n] = *(const short8*)(gB[n] + (size_t)(T) * 32); }
#define RDA1(T, q) { \
    const short* ap = raB + ((T) & 3) * 4096 + (q) * 1024; \
    af[0] = *(const short8*)(ap); af[1] = *(const short8*)(ap + 512); }
#define MFMAQ1(q, X) { \
    __builtin_amdgcn_s_setprio(1); \
    _Pragma("unroll") for (int n = 0; n < NF; n++) { \
      acc[2*(q)][n]   = __builtin_amdgcn_mfma_f32_16x16x32_bf16(X[n], af[0], acc[2*(q)][n], 0, 0, 0); \
      acc[2*(q)+1][n] = __builtin_amdgcn_mfma_f32_16x16x32_bf16(X[n], af[1], acc[2*(q)+1][n], 0, 0, 0); } \
    __builtin_amdgcn_s_setprio(0); }
#define VMW_S  { if constexpr (NF == 4) { VMW(5) } else { VMW(3) } }
#define VMW_P2 { if constexpr (NF == 4) { VMW(4) } else { VMW(2) } }
#define BARX1 { __builtin_amdgcn_s_barrier(); __builtin_amdgcn_sched_barrier(0x0E); }
#define TILE(T, X, Y) { \
    RDA1(T, 0); LDB((T) + 1, Y); STGA1((T) + 2); VMW_S; BARX1; \
    MFMAQ1(0, X); RDA1(T, 1); MFMAQ1(1, X); }
#define TILE_P2(T, X, Y) { \
    RDA1(T, 0); LDB((T) + 1, Y); VMW_P2; BARX1; \
    MFMAQ1(0, X); RDA1(T, 1); MFMAQ1(1, X); }
#define TILE_LAST(T, X) { \
    RDA1(T, 0); VMW(0); \
    MFMAQ1(0, X); RDA1(T, 1); MFMAQ1(1, X); }

  // prologue: B(0)->bA [NF], A(0) [1], A(1) [1]; VMW(1) completes B(0)+A(0)
  LDB(0, bA); STGA1(0); STGA1(1);
  VMW(1);
  __builtin_amdgcn_s_barrier();

  for (int i = 0; i < (NT - 2) / 2; ++i) {
    TILE(2 * i,     bA, bB);
    TILE(2 * i + 1, bB, bA);
  }
  TILE_P2(NT - 2, bA, bB);
  TILE_LAST(NT - 1, bB);
#undef STGA1
#undef LDB
#undef RDA1
#undef MFMAQ1
#undef VMW_S
#undef VMW_P2
#undef BARX1
#undef TILE
#undef TILE_P2
#undef TILE_LAST

  int row0 = bm * 128 + wr * 64, col0 = bn * (NF * 64) + wn * (NF * 16);
#pragma unroll
  for (int n = 0; n < NF; n++) {
    f32x4 bz = *(const f32x4*)(bias + col0 + n * 16 + g * 4);
#pragma unroll
    for (int m = 0; m < 4; m++)
#pragma unroll
      for (int r = 0; r < 4; r++) acc[m][n][r] += bz[r];
  }
  if (EPI == 0) {
    bool insm = (bn * (NF * 64) < smLimit);    // block-uniform
    if constexpr (NF == 4) {
      if (insm) {
#pragma unroll
        for (int m = 0; m < 4; m++) {
          float mx = acc[m][0][0];
#pragma unroll
          for (int n = 0; n < 4; n++)
#pragma unroll
            for (int r = 0; r < 4; r++) mx = fmaxf(mx, acc[m][n][r]);
          mx = fmaxf(mx, __shfl_xor(mx, 16));
          mx = fmaxf(mx, __shfl_xor(mx, 32));
          float s = 0.0f;
#pragma unroll
          for (int n = 0; n < 4; n++)
#pragma unroll
            for (int r = 0; r < 4; r++) {
              float e = __expf(acc[m][n][r] - mx);
              acc[m][n][r] = e; s += e;
            }
          s += __shfl_xor(s, 16);
          s += __shfl_xor(s, 32);
          float inv = 1.0f / s;
#pragma unroll
          for (int n = 0; n < 4; n++)
#pragma unroll
            for (int r = 0; r < 4; r++) acc[m][n][r] *= inv;
        }
      }
    } else {
      // NF=2: 64-col head chunk spans wave pair (wave, wave^1). Exchange
      // partial max/sum via LDS (As reused; __syncthreads provides fences).
      if (insm) {
        float* xch = (float*)As;               // [8 waves][4 m][16 l15]
        float pm[4], ps[4];
#pragma unroll
        for (int m = 0; m < 4; m++) {
          float mx = acc[m][0][0];
#pragma unroll
          for (int n = 0; n < 2; n++)
#pragma unroll
            for (int r = 0; r < 4; r++) mx = fmaxf(mx, acc[m][n][r]);
          mx = fmaxf(mx, __shfl_xor(mx, 16));
          mx = fmaxf(mx, __shfl_xor(mx, 32));
          pm[m] = mx;
        }
        __syncthreads();
        if (g == 0)
#pragma unroll
          for (int m = 0; m < 4; m++) xch[wave * 64 + m * 16 + l15] = pm[m];
        __syncthreads();
#pragma unroll
        for (int m = 0; m < 4; m++)
          pm[m] = fmaxf(pm[m], xch[(wave ^ 1) * 64 + m * 16 + l15]);
#pragma unroll
        for (int m = 0; m < 4; m++) {
          float s = 0.0f;
#pragma unroll
          for (int n = 0; n < 2; n++)
#pragma unroll
            for (int r = 0; r < 4; r++) {
              float e = __expf(acc[m][n][r] - pm[m]);
              acc[m][n][r] = e; s += e;
            }
          s += __shfl_xor(s, 16);
          s += __shfl_xor(s, 32);
          ps[m] = s;
        }
        __syncthreads();
        if (g == 0)
#pragma unroll
          for (int m = 0; m < 4; m++) xch[wave * 64 + m * 16 + l15] = ps[m];
        __syncthreads();
#pragma unroll
        for (int m = 0; m < 4; m++) {
          float inv = 1.0f / (ps[m] + xch[(wave ^ 1) * 64 + m * 16 + l15]);
#pragma unroll
          for (int n = 0; n < 2; n++)
#pragma unroll
            for (int r = 0; r < 4; r++) acc[m][n][r] *= inv;
        }
      }
    }
  }
  if (EPI == 0 && ksumP != nullptr) {
    unsigned rel = (unsigned)(col0 - csBase);
    if (rel < 512u) {
      float* kp = ksumP + ((row0 / Trows) * 8 + (int)(rel >> 6)) * 64 + (int)(rel & 63u);
#pragma unroll
      for (int n = 0; n < NF; n++) {
        f32x4 s = acc[0][n];
#pragma unroll
        for (int m = 1; m < 4; m++)
#pragma unroll
          for (int r = 0; r < 4; r++) s[r] += acc[m][n][r];
#pragma unroll
        for (int msk = 1; msk < 16; msk <<= 1)
#pragma unroll
          for (int r = 0; r < 4; r++) s[r] += __shfl_xor(s[r], msk);
        if (l15 == 0)
#pragma unroll
          for (int r = 0; r < 4; r++)
            atomicAdd(kp + n * 16 + g * 4 + r, s[r]);
      }
    }
  }
  if (EPI == 1) {
#pragma unroll
    for (int m = 0; m < 4; m++)
#pragma unroll
      for (int n = 0; n < NF; n++)
#pragma unroll
        for (int r = 0; r < 4; r++) acc[m][n][r] = gelu_fast(acc[m][n][r]);
  }
#pragma unroll
  for (int m = 0; m < 4; m++) {
    int row = row0 + m * 16 + l15;
#pragma unroll
    for (int n = 0; n < NF; n++) {
      size_t base = (size_t)row * N + col0 + n * 16 + g * 4;
      if (EPI == 2) {
        f32x4 rv = *(const f32x4*)(resid + base);
        f32x4 o;
#pragma unroll
        for (int r = 0; r < 4; r++) o[r] = rv[r] + acc[m][n][r];
        *(f32x4*)((float*)outp + base) = o;
      } else {
        uint2 u;
        u.x = pk2(acc[m][n][0], acc[m][n][1]);
        u.y = pk2(acc[m][n][2], acc[m][n][3]);
        *(uint2*)((unsigned short*)outp + base) = u;
      }
    }
  }
}

// ---------------- ctx += k^T v per (b,h); grid = 32*parts, atomics into zeroed ctx
#define LDC 40
__launch_bounds__(256)
__global__ void ctx_kernel(const short* __restrict__ k, const short* __restrict__ v,
                           float* __restrict__ ctx, int T, int parts, int SD)
{
  __shared__ short kT[4][64 * LDC];
  __shared__ short vT[4][64 * LDC];
  int bh = blockIdx.x & 31, part = blockIdx.x >> 5;
  int b = bh >> 3, h = bh & 7;
  int tid = threadIdx.x, lane = tid & 63, wave = tid >> 6;
  int l15 = lane & 15, g = lane >> 4;
  int tlen = T / (4 * parts);
  int tbeg = (part * 4 + wave) * tlen;
  f32x4 acc[4][4] = {};
  short* myK = kT[wave];
  short* myV = vT[wave];
  for (int t0 = tbeg; t0 < tbeg + tlen; t0 += 32) {
#pragma unroll
    for (int j = 0; j < 4; j++) {
      int c = lane + j * 64;
      int r = c >> 3, d0 = (c & 7) * 8;
      short8 kv = *(const short8*)(k + (size_t)(b * T + t0 + r) * SD + h * 64 + d0);
      short8 vv = *(const short8*)(v + (size_t)(b * T + t0 + r) * SD + h * 64 + d0);
#pragma unroll
      for (int i = 0; i < 8; i++) {
        myK[(d0 + i) * LDC + r] = kv[i];
        myV[(d0 + i) * LDC + r] = vv[i];
      }
    }
    __syncthreads();
    short8 af[4], bfr[4];
#pragma unroll
    for (int m = 0; m < 4; m++) af[m]  = *(const short8*)(myK + (m * 16 + l15) * LDC + g * 8);
#pragma unroll
    for (int n = 0; n < 4; n++) bfr[n] = *(const short8*)(myV + (n * 16 + l15) * LDC + g * 8);
#pragma unroll
    for (int m = 0; m < 4; m++)
#pragma unroll
      for (int n = 0; n < 4; n++)
        acc[m][n] = __builtin_amdgcn_mfma_f32_16x16x32_bf16(af[m], bfr[n], acc[m][n], 0, 0, 0);
    __syncthreads();
  }
  float* cp = ctx + (size_t)bh * 64 * 64;
#pragma unroll
  for (int m = 0; m < 4; m++)
#pragma unroll
    for (int n = 0; n < 4; n++)
#pragma unroll
      for (int r = 0; r < 4; r++)
        atomicAdd(cp + (m * 16 + g * 4 + r) * 64 + (n * 16 + l15), acc[m][n][r]);
}

// ---------------- out[t,:] = q[t,:] + sum_br dinv(t) * (q[t,:] @ ctx[br])
#define LQ 72
__launch_bounds__(256)
__global__ void qctx_kernel(const short* __restrict__ q,
                            const float* __restrict__ ctx,   // [nb][32][64][64]
                            const float* __restrict__ ksum,  // [nb][32][64]
                            short* __restrict__ outp, int T, int nb, int SD)
{
  __shared__ short qs[128 * LQ];
  __shared__ short cT[2][64 * LQ];
  __shared__ float dls[2][128];
  int ntb = T >> 7;
  int bh = blockIdx.x / ntb, tq = blockIdx.x % ntb;
  int b = bh >> 3, h = bh & 7;
  int tid = threadIdx.x, lane = tid & 63, wave = tid >> 6;
  int l15 = lane & 15, g = lane >> 4;
  size_t qbase = (size_t)(b * T + tq * 128) * SD + h * 64;
  size_t obase = (size_t)(b * T + tq * 128) * CDIM + h * 64;

#pragma unroll
  for (int j = 0; j < 4; j++) {
    int c = tid + j * 256;
    int r = c >> 3, d0 = (c & 7) * 8;
    *(short8*)(qs + r * LQ + d0) = *(const short8*)(q + qbase + (size_t)r * SD + d0);
  }
  for (int br = 0; br < nb; br++) {
    const float* cp = ctx + ((size_t)br * 32 + bh) * 4096;
#pragma unroll
    for (int j = 0; j < 16; j++) {
      int e2 = tid + j * 256;
      int dd = e2 >> 6, ee = e2 & 63;
      cT[br][ee * LQ + dd] = f2b(cp[e2]);
    }
  }
  __syncthreads();

  int r0 = wave * 32;
  for (int br = 0; br < nb; br++) {
    int row = r0 + (lane >> 1);
    int dbase = (lane & 1) * 32;
    const float* kp = ksum + ((size_t)br * 32 + bh) * 64 + dbase;
    float s = 0.0f;
#pragma unroll
    for (int d = 0; d < 32; d++)
      s += b2f(qs[row * LQ + dbase + d]) * kp[d];
    s += __shfl_xor(s, 1);
    if (!(lane & 1)) dls[br][row] = 1.0f / fmaxf(s, 1e-9f);
  }

  short8 af[2][2];
#pragma unroll
  for (int m = 0; m < 2; m++)
#pragma unroll
    for (int kk = 0; kk < 2; kk++)
      af[m][kk] = *(const short8*)(qs + (r0 + m * 16 + l15) * LQ + kk * 32 + g * 8);

  float ofin[2][4][4];
#pragma unroll
  for (int m = 0; m < 2; m++)
#pragma unroll
    for (int n = 0; n < 4; n++)
#pragma unroll
      for (int r = 0; r < 4; r++)
        ofin[m][n][r] = b2f(qs[(r0 + m * 16 + g * 4 + r) * LQ + n * 16 + l15]);

  for (int br = 0; br < nb; br++) {
    f32x4 acc[2][4] = {};
#pragma unroll
    for (int kk = 0; kk < 2; kk++) {
      short8 bfr[4];
#pragma unroll
      for (int n = 0; n < 4; n++)
        bfr[n] = *(const short8*)(cT[br] + (n * 16 + l15) * LQ + kk * 32 + g * 8);
#pragma unroll
      for (int m = 0; m < 2; m++)
#pragma unroll
        for (int n = 0; n < 4; n++)
          acc[m][n] = __builtin_amdgcn_mfma_f32_16x16x32_bf16(af[m][kk], bfr[n], acc[m][n], 0, 0, 0);
    }
#pragma unroll
    for (int m = 0; m < 2; m++)
#pragma unroll
      for (int n = 0; n < 4; n++)
#pragma unroll
        for (int r = 0; r < 4; r++)
          ofin[m][n][r] += dls[br][r0 + m * 16 + g * 4 + r] * acc[m][n][r];
  }

#pragma unroll
  for (int m = 0; m < 2; m++)
#pragma unroll
    for (int n = 0; n < 4; n++)
#pragma unroll
      for (int r = 0; r < 4; r++) {
        int row = r0 + m * 16 + g * 4 + r;
        int col = n * 16 + l15;
        outp[obase + (size_t)row * CDIM + col] = f2b(ofin[m][n][r]);
      }
}

extern "C" void kernel_launch(void* const* d_in, const int* in_sizes, int n_in,
                              void* d_out, int out_size, void* d_ws, size_t ws_size,
                              hipStream_t stream)
{
  (void)in_sizes; (void)n_in; (void)out_size; (void)ws_size;
  const float* x     = (const float*)d_in[0];
  const float* y0    = (const float*)d_in[1];
  const float* y1    = (const float*)d_in[2];
  const float* ln1g  = (const float*)d_in[3];
  const float* ln1b  = (const float*)d_in[4];
  const float* ln20g = (const float*)d_in[5];
  const float* ln20b = (const float*)d_in[6];
  const float* ln21g = (const float*)d_in[7];
  const float* ln21b = (const float*)d_in[8];
  const float* ln3g  = (const float*)d_in[9];
  const float* ln3b  = (const float*)d_in[10];
  const float* ln4g  = (const float*)d_in[11];
  const float* ln4b  = (const float*)d_in[12];
  const float* ln5g  = (const float*)d_in[13];
  const float* ln5b  = (const float*)d_in[14];
  const float* caqw  = (const float*)d_in[15];
  const float* caqb  = (const float*)d_in[16];
  const float* cak0w = (const float*)d_in[17];
  const float* cak0b = (const float*)d_in[18];
  const float* cav0w = (const float*)d_in[19];
  const float* cav0b = (const float*)d_in[20];
  const float* cak1w = (const float*)d_in[21];
  const float* cak1b = (const float*)d_in[22];
  const float* cav1w = (const float*)d_in[23];
  const float* cav1b = (const float*)d_in[24];
  const float* capw  = (const float*)d_in[25];
  const float* capb  = (const float*)d_in[26];
  const float* saqw  = (const float*)d_in[27];
  const float* saqb  = (const float*)d_in[28];
  const float* sakw  = (const float*)d_in[29];
  const float* sakb  = (const float*)d_in[30];
  const float* savw  = (const float*)d_in[31];
  const float* savb  = (const float*)d_in[32];
  const float* sapw  = (const float*)d_in[33];
  const float* sapb  = (const float*)d_in[34];
  const float* m1w1  = (const float*)d_in[35];
  const float* m1b1  = (const float*)d_in[36];
  const float* m1w2  = (const float*)d_in[37];
  const float* m1b2  = (const float*)d_in[38];
  const float* m2w1  = (const float*)d_in[39];
  const float* m2b1  = (const float*)d_in[40];
  const float* m2w2  = (const float*)d_in[41];
  const float* m2b2  = (const float*)d_in[42];
  float* xout = (float*)d_out;

  char* p = (char*)d_ws;
  size_t off = 0;
  auto take = [&](size_t bytes) {
    char* r = p + off;
    off += (bytes + 255) & ~(size_t)255;
    return r;
  };
  const size_t W512 = (size_t)512 * 512 * 2;
  const size_t WMLP = (size_t)2048 * 512 * 2;
  short* wt_caq   = (short*)take(W512);
  short* wt_cakv0 = (short*)take(2 * W512);       // [k;v] 1024x512
  short* wt_cakv1 = (short*)take(2 * W512);
  short* wt_cap   = (short*)take(W512);
  short* wt_saqkv = (short*)take(3 * W512);       // [q;k;v] 1536x512
  short* wt_sap   = (short*)take(W512);
  short* wt_m1w1  = (short*)take(WMLP);
  short* wt_m1w2  = (short*)take(WMLP);
  short* wt_m2w1  = (short*)take(WMLP);
  short* wt_m2w2  = (short*)take(WMLP);
  float* b_saqkv  = (float*)take(1536 * 4);
  float* b_cakv0  = (float*)take(1024 * 4);
  float* b_cakv1  = (float*)take(1024 * 4);
  short* xn   = (short*)take((size_t)16384 * 512 * 2);
  short* bufD = (short*)take((size_t)16384 * 512 * 2);
  short* big  = (short*)take((size_t)16384 * 1536 * 2);   // CA: q@0, kv@+8M shorts; SA: qkv
  short* h1   = (short*)take((size_t)16384 * 2048 * 2);
  float* ksum = (float*)take((size_t)2 * 32 * 64 * 4);
  float* ctxb = (float*)take((size_t)2 * 32 * 64 * 64 * 4);

  short* q_ca  = big;
  short* kv_ca = big + (size_t)8 * 1024 * 1024;
  short* qkv   = big;

  const int MQ  = NBATCH * TQD;   // 16384
  const int MKV = NBATCH * TBD;   // 8192

  // ---- weight transpose+convert (single batched launch) ----
  {
    TcvtDesc d;
    const float* srcs[14] = {caqw, cak0w, cav0w, cak1w, cav1w, capw,
                             saqw, sakw, savw, sapw, m1w1, m1w2, m2w1, m2w2};
    short* dsts[14] = {wt_caq, wt_cakv0, wt_cakv0 + 512 * 512,
                       wt_cakv1, wt_cakv1 + 512 * 512, wt_cap,
                       wt_saqkv, wt_saqkv + 512 * 512, wt_saqkv + 2 * 512 * 512, wt_sap,
                       wt_m1w1, wt_m1w2, wt_m2w1, wt_m2w2};
    int Ks[14] = {512,512,512,512,512,512,512,512,512,512, 512,2048,512,2048};
    int Ns[14] = {512,512,512,512,512,512,512,512,512,512, 2048,512,2048,512};
    int total = 0;
    for (int i = 0; i < 14; i++) {
      d.src[i] = srcs[i]; d.dst[i] = dsts[i]; d.K[i] = Ks[i]; d.N[i] = Ns[i];
      d.nblk[i] = (Ks[i] >> 5) * (Ns[i] >> 5);
      total += d.nblk[i];
    }
    tcvt_all<<<total, 256, 0, stream>>>(d);
  }
  // ---- bias concats ----
  hipMemcpyAsync(b_saqkv,        saqb,  512 * 4, hipMemcpyDeviceToDevice, stream);
  hipMemcpyAsync(b_saqkv + 512,  sakb,  512 * 4, hipMemcpyDeviceToDevice, stream);
  hipMemcpyAsync(b_saqkv + 1024, savb,  512 * 4, hipMemcpyDeviceToDevice, stream);
  hipMemcpyAsync(b_cakv0,        cak0b, 512 * 4, hipMemcpyDeviceToDevice, stream);
  hipMemcpyAsync(b_cakv0 + 512,  cav0b, 512 * 4, hipMemcpyDeviceToDevice, stream);
  hipMemcpyAsync(b_cakv1,        cak1b, 512 * 4, hipMemcpyDeviceToDevice, stream);
  hipMemcpyAsync(b_cakv1 + 512,  cav1b, 512 * 4, hipMemcpyDeviceToDevice, stream);

  // ---- cross-attention ----
  ln_kernel<<<MQ / 4, 256, 0, stream>>>(x, ln1g, ln1b, xn);
  hipMemsetAsync(ksum, 0, (size_t)2 * 32 * 64 * 4, stream);
  hipMemsetAsync(ctxb, 0, (size_t)2 * 32 * 64 * 64 * 4, stream);
  gemm128<0, 2, 512><<<512, 512, 0, stream>>>(xn, wt_caq, caqb, nullptr, q_ca,
                                              MQ, 512, 512, nullptr, 0, 0);
  for (int br = 0; br < 2; br++) {
    const float* yy = br ? y1 : y0;
    const float* lg = br ? ln21g : ln20g;
    const float* lb = br ? ln21b : ln20b;
    const short* wk = br ? wt_cakv1 : wt_cakv0;
    const float* bk = br ? b_cakv1 : b_cakv0;
    ln_kernel<<<MKV / 4, 256, 0, stream>>>(yy, lg, lb, bufD);
    gemm128<0, 2, 512><<<512, 512, 0, stream>>>(bufD, wk, bk, nullptr, kv_ca,
                                                MKV, 1024, 512,
                                                ksum + (size_t)br * 2048, 0, TBD);
    ctx_kernel<<<256, 256, 0, stream>>>(kv_ca, kv_ca + 512,
                                        ctxb + (size_t)br * 32 * 4096, TBD, 8, 1024);
  }
  qctx_kernel<<<32 * (TQD / 128), 256, 0, stream>>>(q_ca, ctxb, ksum, bufD, TQD, 2, 512);
  gemm128<2, 2, 512><<<512, 512, 0, stream>>>(bufD, wt_cap, capb, x, xout,
                                              MQ, 512, 0, nullptr, 0, 0);

  // ---- MLP 1 ----
  ln_kernel<<<MQ / 4, 256, 0, stream>>>(xout, ln3g, ln3b, xn);
  gemm128<1, 4, 512><<<1024, 512, 0, stream>>>(xn, wt_m1w1, m1b1, nullptr, h1,
                                               MQ, 2048, 0, nullptr, 0, 0);
  gemm128<2, 2, 2048><<<512, 512, 0, stream>>>(h1, wt_m1w2, m1b2, xout, xout,
                                               MQ, 512, 0, nullptr, 0, 0);

  // ---- self-attention (fused q|k|v projection; k-colsum fused) ----
  ln_kernel<<<MQ / 4, 256, 0, stream>>>(xout, ln4g, ln4b, xn);
  hipMemsetAsync(ksum, 0, (size_t)32 * 64 * 4, stream);
  hipMemsetAsync(ctxb, 0, (size_t)32 * 64 * 64 * 4, stream);
  gemm128<0, 4, 512><<<768, 512, 0, stream>>>(xn, wt_saqkv, b_saqkv, nullptr, qkv,
                                              MQ, 1536, 1024, ksum, 512, TQD);
  ctx_kernel<<<256, 256, 0, stream>>>(qkv + 512, qkv + 1024, ctxb, TQD, 8, 1536);
  qctx_kernel<<<32 * (TQD / 128), 256, 0, stream>>>(qkv, ctxb, ksum, bufD, TQD, 1, 1536);
  gemm128<2, 2, 512><<<512, 512, 0, stream>>>(bufD, wt_sap, sapb, xout, xout,
                                              MQ, 512, 0, nullptr, 0, 0);

  // ---- MLP 2 ----
  ln_kernel<<<MQ / 4, 256, 0, stream>>>(xout, ln5g, ln5b, xn);
  gemm128<1, 4, 512><<<1024, 512, 0, stream>>>(xn, wt_m2w1, m2b1, nullptr, h1,
                                               MQ, 2048, 0, nullptr, 0, 0);
  gemm128<2, 2, 2048><<<512, 512, 0, stream>>>(h1, wt_m2w2, m2b2, xout, xout,
                                               MQ, 512, 0, nullptr, 0, 0);
}

// Round 12
// 540.274 us; speedup vs baseline: 1.3002x; 1.3002x over previous
//
#include <hip/hip_runtime.h>
#include <hip/hip_bf16.h>
#include <math.h>

// Problem constants
#define NBATCH 4
#define TQD 4096
#define TBD 2048
#define CDIM 512
#define NH 8
#define HD 64
#define NINNER 2048

using short8 = __attribute__((ext_vector_type(8))) short;
using f32x4  = __attribute__((ext_vector_type(4))) float;

__device__ __forceinline__ float b2f(short s) {
  return __uint_as_float(((unsigned)(unsigned short)s) << 16);
}
__device__ __forceinline__ short f2b(float f) {
  unsigned u = __float_as_uint(f);
  return (short)((u + 0x7FFFu + ((u >> 16) & 1u)) >> 16);
}
__device__ __forceinline__ unsigned pk2(float a, float b) {
  float2 t; t.x = a; t.y = b;
  __hip_bfloat162 h = __float22bfloat162_rn(t);
  return *(unsigned*)&h;
}
__device__ __forceinline__ float gelu_fast(float x) {
  float x3 = x * x * x;
  float y2 = 1.5957691216f * (x + 0.044715f * x3);
  float e = __expf(y2);
  return x * e / (e + 1.0f);
}
// fragment-packed layout for a R x K bf16 matrix (MFMA operand order):
// [rg = r>>4][kg = k>>5][lane = (r&15) + 16*((k>>3)&3)][e = k&7]
// => one fragment = 1KB contiguous; lane L holds row L&15, k = 8*(L>>4)+e
// (exactly the 16x16x32 operand layout). Offset in shorts:
__device__ __forceinline__ size_t paOff(int r, int k, int NKG) {
  return ((size_t)((r >> 4) * NKG + (k >> 5)) * 64 + (r & 15) + 16 * ((k >> 3) & 3)) * 8
         + (k & 7);
}

// ---------------- LayerNorm (fp32 in -> PACKED bf16 out), wave-per-row
__launch_bounds__(256)
__global__ void ln_kernel(const float* __restrict__ x, const float* __restrict__ g,
                          const float* __restrict__ b, short* __restrict__ out)
{
  int row = blockIdx.x * 4 + (threadIdx.x >> 6);
  int lane = threadIdx.x & 63;
  const float4* xp = (const float4*)(x + (size_t)row * CDIM);
  float4 v0 = xp[2 * lane], v1 = xp[2 * lane + 1];   // k in [8*lane, 8*lane+8)
  float s  = v0.x + v0.y + v0.z + v0.w + v1.x + v1.y + v1.z + v1.w;
  float s2 = v0.x * v0.x + v0.y * v0.y + v0.z * v0.z + v0.w * v0.w
           + v1.x * v1.x + v1.y * v1.y + v1.z * v1.z + v1.w * v1.w;
#pragma unroll
  for (int m = 1; m < 64; m <<= 1) { s += __shfl_xor(s, m); s2 += __shfl_xor(s2, m); }
  float mean = s * (1.0f / CDIM);
  float var  = s2 * (1.0f / CDIM) - mean * mean;
  float inv  = rsqrtf(var + 1e-5f);
  float4 g0 = ((const float4*)g)[2 * lane], g1 = ((const float4*)g)[2 * lane + 1];
  float4 b0 = ((const float4*)b)[2 * lane], b1 = ((const float4*)b)[2 * lane + 1];
  uint4 o;
  o.x = pk2((v0.x - mean) * inv * g0.x + b0.x, (v0.y - mean) * inv * g0.y + b0.y);
  o.y = pk2((v0.z - mean) * inv * g0.z + b0.z, (v0.w - mean) * inv * g0.w + b0.w);
  o.z = pk2((v1.x - mean) * inv * g1.x + b1.x, (v1.y - mean) * inv * g1.y + b1.y);
  o.w = pk2((v1.z - mean) * inv * g1.z + b1.z, (v1.w - mean) * inv * g1.w + b1.w);
  *(uint4*)(out + paOff(row, 8 * lane, CDIM >> 5)) = o;
}

// ---------------- batched transpose+convert: W[K][N] f32 -> PACKED Wt (N x K)
struct TcvtDesc {
  const float* src[14];
  short* dst[14];
  int K[14], N[14], nblk[14];
};
__launch_bounds__(256)
__global__ void tcvt_all(TcvtDesc d)
{
  int blk = blockIdx.x, wi = 0;
  while (blk >= d.nblk[wi]) { blk -= d.nblk[wi]; wi++; }
  const float* __restrict__ W = d.src[wi];
  short* __restrict__ Wt = d.dst[wi];
  int K = d.K[wi], N = d.N[wi];
  __shared__ float t[32][33];
  int nbk = K >> 5;
  int bk = blk % nbk, bn = blk / nbk;
  int cx = threadIdx.x & 31, cy = threadIdx.x >> 5;
#pragma unroll
  for (int i = 0; i < 4; i++)
    t[cy + 8 * i][cx] = W[(size_t)(bk * 32 + cy + 8 * i) * N + bn * 32 + cx];
  __syncthreads();
#pragma unroll
  for (int i = 0; i < 4; i++) {
    int n = bn * 32 + cy + 8 * i, k = bk * 32 + cx;
    Wt[paOff(n, k, K >> 5)] = f2b(t[cx][cy + 8 * i]);
  }
}

// ======== 128x128 direct-register GEMM: ZERO LDS, ZERO barriers ============
// A, Bt fragment-packed (paOff layout). 4 waves (2wr x 2wn), wave tile 64x64:
// 4 A-frags + 4 B-frags per K-tile (kg), 16 MFMA. X/Y register double-buffer;
// waves fully independent -> compiler's automatic counted vmcnt is exact and
// optimal (no LDS drains, no publish hazards). 3 blocks/CU via (256,3).
// EPI: 0 = bf16 row-major + in-wave softmax per 64-col chunk where col<smLimit
//      (+fused k-colsum when ksumP!=null, cols [csBase,csBase+512));
//      1 = gelu, PACKED bf16 out (next GEMM's A); 2 = residual-add fp32.
template<int EPI, int KK>
__launch_bounds__(256, 3)
__global__ void gemmd(const short* __restrict__ A, const short* __restrict__ Bt,
                      const float* __restrict__ bias, const float* __restrict__ resid,
                      void* __restrict__ outp, int M, int N, int smLimit,
                      float* __restrict__ ksumP, int csBase, int Trows)
{
  constexpr int NKG = KK >> 5;
  constexpr int NT = NKG;
  int tid = threadIdx.x, lane = tid & 63, wave = tid >> 6;
  int l15 = lane & 15, g = lane >> 4;
  int wr = wave >> 1, wn = wave & 1;
  int nbn = N >> 7;
  int per = gridDim.x >> 3;
  int wg = (blockIdx.x & 7) * per + (blockIdx.x >> 3);
  int bm = wg / nbn, bn = wg % nbn;
  f32x4 acc[4][4] = {};

  const short* pa = A  + (size_t)(bm * 8 + wr * 4) * NKG * 512 + lane * 8;
  const short* pb = Bt + (size_t)(bn * 8 + wn * 4) * NKG * 512 + lane * 8;

  short8 X[8], Y[8];
#define LDF(kg, Z) { \
    _Pragma("unroll") for (int f = 0; f < 4; f++) { \
      Z[f]     = *(const short8*)(pa + ((size_t)f * NKG + (kg)) * 512); \
      Z[4 + f] = *(const short8*)(pb + ((size_t)f * NKG + (kg)) * 512); } }
#define CMP(Z) { \
    __builtin_amdgcn_s_setprio(1); \
    _Pragma("unroll") for (int mq = 0; mq < 4; mq++) \
      _Pragma("unroll") for (int nq = 0; nq < 4; nq++) \
        acc[mq][nq] = __builtin_amdgcn_mfma_f32_16x16x32_bf16(Z[4 + nq], Z[mq], acc[mq][nq], 0, 0, 0); \
    __builtin_amdgcn_s_setprio(0); }

  LDF(0, X); LDF(1, Y);
#pragma unroll 2
  for (int t = 0; t < NT - 2; t += 2) {
    CMP(X); LDF(t + 2, X);
    CMP(Y); LDF(t + 3, Y);
  }
  CMP(X); CMP(Y);
#undef LDF
#undef CMP

  int row0 = bm * 128 + wr * 64, col0 = bn * 128 + wn * 64;
#pragma unroll
  for (int n = 0; n < 4; n++) {
    f32x4 bz = *(const f32x4*)(bias + col0 + n * 16 + g * 4);
#pragma unroll
    for (int m = 0; m < 4; m++)
#pragma unroll
      for (int r = 0; r < 4; r++) acc[m][n][r] += bz[r];
  }
  if (EPI == 0 && col0 < smLimit) {
    // softmax over the wave's 64-col head chunk: 16 in-lane + lanes {l15,+16,+32,+48}
#pragma unroll
    for (int m = 0; m < 4; m++) {
      float mx = acc[m][0][0];
#pragma unroll
      for (int n = 0; n < 4; n++)
#pragma unroll
        for (int r = 0; r < 4; r++) mx = fmaxf(mx, acc[m][n][r]);
      mx = fmaxf(mx, __shfl_xor(mx, 16));
      mx = fmaxf(mx, __shfl_xor(mx, 32));
      float s = 0.0f;
#pragma unroll
      for (int n = 0; n < 4; n++)
#pragma unroll
        for (int r = 0; r < 4; r++) {
          float e = __expf(acc[m][n][r] - mx);
          acc[m][n][r] = e; s += e;
        }
      s += __shfl_xor(s, 16);
      s += __shfl_xor(s, 32);
      float inv = 1.0f / s;
#pragma unroll
      for (int n = 0; n < 4; n++)
#pragma unroll
        for (int r = 0; r < 4; r++) acc[m][n][r] *= inv;
    }
  }
  if (EPI == 0 && ksumP != nullptr) {
    unsigned rel = (unsigned)(col0 - csBase);
    if (rel < 512u) {
      float* kp = ksumP + ((row0 / Trows) * 8 + (int)(rel >> 6)) * 64;
#pragma unroll
      for (int n = 0; n < 4; n++) {
        f32x4 s = acc[0][n];
#pragma unroll
        for (int m = 1; m < 4; m++)
#pragma unroll
          for (int r = 0; r < 4; r++) s[r] += acc[m][n][r];
#pragma unroll
        for (int msk = 1; msk < 16; msk <<= 1)
#pragma unroll
          for (int r = 0; r < 4; r++) s[r] += __shfl_xor(s[r], msk);
        if (l15 == 0)
#pragma unroll
          for (int r = 0; r < 4; r++)
            atomicAdd(kp + n * 16 + g * 4 + r, s[r]);
      }
    }
  }
#pragma unroll
  for (int m = 0; m < 4; m++) {
    int row = row0 + m * 16 + l15;
#pragma unroll
    for (int n = 0; n < 4; n++) {
      if (EPI == 2) {
        size_t base = (size_t)row * N + col0 + n * 16 + g * 4;
        f32x4 rv = *(const f32x4*)(resid + base);
        f32x4 o;
#pragma unroll
        for (int r = 0; r < 4; r++) o[r] = rv[r] + acc[m][n][r];
        *(f32x4*)((float*)outp + base) = o;
      } else if (EPI == 1) {
        // gelu + PACKED store (this output is the next GEMM's A, K-dim = N)
        int k0 = col0 + n * 16 + g * 4;
        uint2 u;
        u.x = pk2(gelu_fast(acc[m][n][0]), gelu_fast(acc[m][n][1]));
        u.y = pk2(gelu_fast(acc[m][n][2]), gelu_fast(acc[m][n][3]));
        *(uint2*)((short*)outp + paOff(row, k0, N >> 5)) = u;
      } else {
        size_t base = (size_t)row * N + col0 + n * 16 + g * 4;
        uint2 u;
        u.x = pk2(acc[m][n][0], acc[m][n][1]);
        u.y = pk2(acc[m][n][2], acc[m][n][3]);
        *(uint2*)((unsigned short*)outp + base) = u;
      }
    }
  }
}

// ---------------- ctx += k^T v per (b,h); grid = 32*parts, atomics into zeroed ctx
#define LDC 40
__launch_bounds__(256)
__global__ void ctx_kernel(const short* __restrict__ k, const short* __restrict__ v,
                           float* __restrict__ ctx, int T, int parts, int SD)
{
  __shared__ short kT[4][64 * LDC];
  __shared__ short vT[4][64 * LDC];
  int bh = blockIdx.x & 31, part = blockIdx.x >> 5;
  int b = bh >> 3, h = bh & 7;
  int tid = threadIdx.x, lane = tid & 63, wave = tid >> 6;
  int l15 = lane & 15, g = lane >> 4;
  int tlen = T / (4 * parts);
  int tbeg = (part * 4 + wave) * tlen;
  f32x4 acc[4][4] = {};
  short* myK = kT[wave];
  short* myV = vT[wave];
  for (int t0 = tbeg; t0 < tbeg + tlen; t0 += 32) {
#pragma unroll
    for (int j = 0; j < 4; j++) {
      int c = lane + j * 64;
      int r = c >> 3, d0 = (c & 7) * 8;
      short8 kv = *(const short8*)(k + (size_t)(b * T + t0 + r) * SD + h * 64 + d0);
      short8 vv = *(const short8*)(v + (size_t)(b * T + t0 + r) * SD + h * 64 + d0);
#pragma unroll
      for (int i = 0; i < 8; i++) {
        myK[(d0 + i) * LDC + r] = kv[i];
        myV[(d0 + i) * LDC + r] = vv[i];
      }
    }
    __syncthreads();
    short8 af[4], bfr[4];
#pragma unroll
    for (int m = 0; m < 4; m++) af[m]  = *(const short8*)(myK + (m * 16 + l15) * LDC + g * 8);
#pragma unroll
    for (int n = 0; n < 4; n++) bfr[n] = *(const short8*)(myV + (n * 16 + l15) * LDC + g * 8);
#pragma unroll
    for (int m = 0; m < 4; m++)
#pragma unroll
      for (int n = 0; n < 4; n++)
        acc[m][n] = __builtin_amdgcn_mfma_f32_16x16x32_bf16(af[m], bfr[n], acc[m][n], 0, 0, 0);
    __syncthreads();
  }
  float* cp = ctx + (size_t)bh * 64 * 64;
#pragma unroll
  for (int m = 0; m < 4; m++)
#pragma unroll
    for (int n = 0; n < 4; n++)
#pragma unroll
      for (int r = 0; r < 4; r++)
        atomicAdd(cp + (m * 16 + g * 4 + r) * 64 + (n * 16 + l15), acc[m][n][r]);
}

// ---------------- out[t,:] = q[t,:] + sum_br dinv(t) * (q[t,:] @ ctx[br])
// q read row-major; OUTPUT written fragment-PACKED (feeds cap/sap GEMM A).
#define LQ 72
__launch_bounds__(256)
__global__ void qctx_kernel(const short* __restrict__ q,
                            const float* __restrict__ ctx,   // [nb][32][64][64]
                            const float* __restrict__ ksum,  // [nb][32][64]
                            short* __restrict__ outp, int T, int nb, int SD)
{
  __shared__ short qs[128 * LQ];
  __shared__ short cT[2][64 * LQ];
  __shared__ float dls[2][128];
  int ntb = T >> 7;
  int bh = blockIdx.x / ntb, tq = blockIdx.x % ntb;
  int b = bh >> 3, h = bh & 7;
  int tid = threadIdx.x, lane = tid & 63, wave = tid >> 6;
  int l15 = lane & 15, g = lane >> 4;
  size_t qbase = (size_t)(b * T + tq * 128) * SD + h * 64;
  int grow0 = b * T + tq * 128;           // global row base (16-aligned)

#pragma unroll
  for (int j = 0; j < 4; j++) {
    int c = tid + j * 256;
    int r = c >> 3, d0 = (c & 7) * 8;
    *(short8*)(qs + r * LQ + d0) = *(const short8*)(q + qbase + (size_t)r * SD + d0);
  }
  for (int br = 0; br < nb; br++) {
    const float* cp = ctx + ((size_t)br * 32 + bh) * 4096;
#pragma unroll
    for (int j = 0; j < 16; j++) {
      int e2 = tid + j * 256;
      int dd = e2 >> 6, ee = e2 & 63;
      cT[br][ee * LQ + dd] = f2b(cp[e2]);
    }
  }
  __syncthreads();

  int r0 = wave * 32;
  for (int br = 0; br < nb; br++) {
    int row = r0 + (lane >> 1);
    int dbase = (lane & 1) * 32;
    const float* kp = ksum + ((size_t)br * 32 + bh) * 64 + dbase;
    float s = 0.0f;
#pragma unroll
    for (int d = 0; d < 32; d++)
      s += b2f(qs[row * LQ + dbase + d]) * kp[d];
    s += __shfl_xor(s, 1);
    if (!(lane & 1)) dls[br][row] = 1.0f / fmaxf(s, 1e-9f);
  }

  short8 af[2][2];
#pragma unroll
  for (int m = 0; m < 2; m++)
#pragma unroll
    for (int kk = 0; kk < 2; kk++)
      af[m][kk] = *(const short8*)(qs + (r0 + m * 16 + l15) * LQ + kk * 32 + g * 8);

  float ofin[2][4][4];
#pragma unroll
  for (int m = 0; m < 2; m++)
#pragma unroll
    for (int n = 0; n < 4; n++)
#pragma unroll
      for (int r = 0; r < 4; r++)
        ofin[m][n][r] = b2f(qs[(r0 + m * 16 + g * 4 + r) * LQ + n * 16 + l15]);

  for (int br = 0; br < nb; br++) {
    f32x4 acc[2][4] = {};
#pragma unroll
    for (int kk = 0; kk < 2; kk++) {
      short8 bfr[4];
#pragma unroll
      for (int n = 0; n < 4; n++)
        bfr[n] = *(const short8*)(cT[br] + (n * 16 + l15) * LQ + kk * 32 + g * 8);
#pragma unroll
      for (int m = 0; m < 2; m++)
#pragma unroll
        for (int n = 0; n < 4; n++)
          acc[m][n] = __builtin_amdgcn_mfma_f32_16x16x32_bf16(af[m][kk], bfr[n], acc[m][n], 0, 0, 0);
    }
#pragma unroll
    for (int m = 0; m < 2; m++)
#pragma unroll
      for (int n = 0; n < 4; n++)
#pragma unroll
        for (int r = 0; r < 4; r++)
          ofin[m][n][r] += dls[br][r0 + m * 16 + g * 4 + r] * acc[m][n][r];
  }

#pragma unroll
  for (int m = 0; m < 2; m++)
#pragma unroll
    for (int n = 0; n < 4; n++)
#pragma unroll
      for (int r = 0; r < 4; r++) {
        int row = r0 + m * 16 + g * 4 + r;
        int kcol = h * 64 + n * 16 + l15;      // K-dim of the proj GEMM
        outp[paOff(grow0 + row, kcol, CDIM >> 5)] = f2b(ofin[m][n][r]);
      }
}

extern "C" void kernel_launch(void* const* d_in, const int* in_sizes, int n_in,
                              void* d_out, int out_size, void* d_ws, size_t ws_size,
                              hipStream_t stream)
{
  (void)in_sizes; (void)n_in; (void)out_size; (void)ws_size;
  const float* x     = (const float*)d_in[0];
  const float* y0    = (const float*)d_in[1];
  const float* y1    = (const float*)d_in[2];
  const float* ln1g  = (const float*)d_in[3];
  const float* ln1b  = (const float*)d_in[4];
  const float* ln20g = (const float*)d_in[5];
  const float* ln20b = (const float*)d_in[6];
  const float* ln21g = (const float*)d_in[7];
  const float* ln21b = (const float*)d_in[8];
  const float* ln3g  = (const float*)d_in[9];
  const float* ln3b  = (const float*)d_in[10];
  const float* ln4g  = (const float*)d_in[11];
  const float* ln4b  = (const float*)d_in[12];
  const float* ln5g  = (const float*)d_in[13];
  const float* ln5b  = (const float*)d_in[14];
  const float* caqw  = (const float*)d_in[15];
  const float* caqb  = (const float*)d_in[16];
  const float* cak0w = (const float*)d_in[17];
  const float* cak0b = (const float*)d_in[18];
  const float* cav0w = (const float*)d_in[19];
  const float* cav0b = (const float*)d_in[20];
  const float* cak1w = (const float*)d_in[21];
  const float* cak1b = (const float*)d_in[22];
  const float* cav1w = (const float*)d_in[23];
  const float* cav1b = (const float*)d_in[24];
  const float* capw  = (const float*)d_in[25];
  const float* capb  = (const float*)d_in[26];
  const float* saqw  = (const float*)d_in[27];
  const float* saqb  = (const float*)d_in[28];
  const float* sakw  = (const float*)d_in[29];
  const float* sakb  = (const float*)d_in[30];
  const float* savw  = (const float*)d_in[31];
  const float* savb  = (const float*)d_in[32];
  const float* sapw  = (const float*)d_in[33];
  const float* sapb  = (const float*)d_in[34];
  const float* m1w1  = (const float*)d_in[35];
  const float* m1b1  = (const float*)d_in[36];
  const float* m1w2  = (const float*)d_in[37];
  const float* m1b2  = (const float*)d_in[38];
  const float* m2w1  = (const float*)d_in[39];
  const float* m2b1  = (const float*)d_in[40];
  const float* m2w2  = (const float*)d_in[41];
  const float* m2b2  = (const float*)d_in[42];
  float* xout = (float*)d_out;

  char* p = (char*)d_ws;
  size_t off = 0;
  auto take = [&](size_t bytes) {
    char* r = p + off;
    off += (bytes + 255) & ~(size_t)255;
    return r;
  };
  const size_t W512 = (size_t)512 * 512 * 2;
  const size_t WMLP = (size_t)2048 * 512 * 2;
  short* wt_caq   = (short*)take(W512);
  short* wt_cakv0 = (short*)take(2 * W512);       // [k;v] 1024x512
  short* wt_cakv1 = (short*)take(2 * W512);
  short* wt_cap   = (short*)take(W512);
  short* wt_saqkv = (short*)take(3 * W512);       // [q;k;v] 1536x512
  short* wt_sap   = (short*)take(W512);
  short* wt_m1w1  = (short*)take(WMLP);
  short* wt_m1w2  = (short*)take(WMLP);
  short* wt_m2w1  = (short*)take(WMLP);
  short* wt_m2w2  = (short*)take(WMLP);
  float* b_saqkv  = (float*)take(1536 * 4);
  float* b_cakv0  = (float*)take(1024 * 4);
  float* b_cakv1  = (float*)take(1024 * 4);
  short* xn   = (short*)take((size_t)16384 * 512 * 2);     // packed
  short* bufD = (short*)take((size_t)16384 * 512 * 2);     // packed
  short* big  = (short*)take((size_t)16384 * 1536 * 2);    // row-major q/k/v
  short* h1   = (short*)take((size_t)16384 * 2048 * 2);    // packed
  float* ksum = (float*)take((size_t)2 * 32 * 64 * 4);
  float* ctxb = (float*)take((size_t)2 * 32 * 64 * 64 * 4);

  short* q_ca  = big;
  short* kv_ca = big + (size_t)8 * 1024 * 1024;
  short* qkv   = big;

  const int MQ  = NBATCH * TQD;   // 16384
  const int MKV = NBATCH * TBD;   // 8192

  // ---- weight transpose+convert+pack (single batched launch) ----
  {
    TcvtDesc d;
    const float* srcs[14] = {caqw, cak0w, cav0w, cak1w, cav1w, capw,
                             saqw, sakw, savw, sapw, m1w1, m1w2, m2w1, m2w2};
    short* dsts[14] = {wt_caq, wt_cakv0, wt_cakv0 + 512 * 512,
                       wt_cakv1, wt_cakv1 + 512 * 512, wt_cap,
                       wt_saqkv, wt_saqkv + 512 * 512, wt_saqkv + 2 * 512 * 512, wt_sap,
                       wt_m1w1, wt_m1w2, wt_m2w1, wt_m2w2};
    int Ks[14] = {512,512,512,512,512,512,512,512,512,512, 512,2048,512,2048};
    int Ns[14] = {512,512,512,512,512,512,512,512,512,512, 2048,512,2048,512};
    int total = 0;
    for (int i = 0; i < 14; i++) {
      d.src[i] = srcs[i]; d.dst[i] = dsts[i]; d.K[i] = Ks[i]; d.N[i] = Ns[i];
      d.nblk[i] = (Ks[i] >> 5) * (Ns[i] >> 5);
      total += d.nblk[i];
    }
    tcvt_all<<<total, 256, 0, stream>>>(d);
  }
  // ---- bias concats ----
  hipMemcpyAsync(b_saqkv,        saqb,  512 * 4, hipMemcpyDeviceToDevice, stream);
  hipMemcpyAsync(b_saqkv + 512,  sakb,  512 * 4, hipMemcpyDeviceToDevice, stream);
  hipMemcpyAsync(b_saqkv + 1024, savb,  512 * 4, hipMemcpyDeviceToDevice, stream);
  hipMemcpyAsync(b_cakv0,        cak0b, 512 * 4, hipMemcpyDeviceToDevice, stream);
  hipMemcpyAsync(b_cakv0 + 512,  cav0b, 512 * 4, hipMemcpyDeviceToDevice, stream);
  hipMemcpyAsync(b_cakv1,        cak1b, 512 * 4, hipMemcpyDeviceToDevice, stream);
  hipMemcpyAsync(b_cakv1 + 512,  cav1b, 512 * 4, hipMemcpyDeviceToDevice, stream);

  // ---- cross-attention ----
  ln_kernel<<<MQ / 4, 256, 0, stream>>>(x, ln1g, ln1b, xn);
  hipMemsetAsync(ksum, 0, (size_t)2 * 32 * 64 * 4, stream);
  hipMemsetAsync(ctxb, 0, (size_t)2 * 32 * 64 * 64 * 4, stream);
  gemmd<0, 512><<<512, 256, 0, stream>>>(xn, wt_caq, caqb, nullptr, q_ca,
                                         MQ, 512, 512, nullptr, 0, 0);
  for (int br = 0; br < 2; br++) {
    const float* yy = br ? y1 : y0;
    const float* lg = br ? ln21g : ln20g;
    const float* lb = br ? ln21b : ln20b;
    const short* wk = br ? wt_cakv1 : wt_cakv0;
    const float* bk = br ? b_cakv1 : b_cakv0;
    ln_kernel<<<MKV / 4, 256, 0, stream>>>(yy, lg, lb, bufD);
    gemmd<0, 512><<<512, 256, 0, stream>>>(bufD, wk, bk, nullptr, kv_ca,
                                           MKV, 1024, 512,
                                           ksum + (size_t)br * 2048, 0, TBD);
    ctx_kernel<<<256, 256, 0, stream>>>(kv_ca, kv_ca + 512,
                                        ctxb + (size_t)br * 32 * 4096, TBD, 8, 1024);
  }
  qctx_kernel<<<32 * (TQD / 128), 256, 0, stream>>>(q_ca, ctxb, ksum, bufD, TQD, 2, 512);
  gemmd<2, 512><<<512, 256, 0, stream>>>(bufD, wt_cap, capb, x, xout,
                                         MQ, 512, 0, nullptr, 0, 0);

  // ---- MLP 1 ----
  ln_kernel<<<MQ / 4, 256, 0, stream>>>(xout, ln3g, ln3b, xn);
  gemmd<1, 512><<<2048, 256, 0, stream>>>(xn, wt_m1w1, m1b1, nullptr, h1,
                                          MQ, 2048, 0, nullptr, 0, 0);
  gemmd<2, 2048><<<512, 256, 0, stream>>>(h1, wt_m1w2, m1b2, xout, xout,
                                          MQ, 512, 0, nullptr, 0, 0);

  // ---- self-attention (fused q|k|v projection; k-colsum fused) ----
  ln_kernel<<<MQ / 4, 256, 0, stream>>>(xout, ln4g, ln4b, xn);
  hipMemsetAsync(ksum, 0, (size_t)32 * 64 * 4, stream);
  hipMemsetAsync(ctxb, 0, (size_t)32 * 64 * 64 * 4, stream);
  gemmd<0, 512><<<1536, 256, 0, stream>>>(xn, wt_saqkv, b_saqkv, nullptr, qkv,
                                          MQ, 1536, 1024, ksum, 512, TQD);
  ctx_kernel<<<256, 256, 0, stream>>>(qkv + 512, qkv + 1024, ctxb, TQD, 8, 1536);
  qctx_kernel<<<32 * (TQD / 128), 256, 0, stream>>>(qkv, ctxb, ksum, bufD, TQD, 1, 1536);
  gemmd<2, 512><<<512, 256, 0, stream>>>(bufD, wt_sap, sapb, xout, xout,
                                         MQ, 512, 0, nullptr, 0, 0);

  // ---- MLP 2 ----
  ln_kernel<<<MQ / 4, 256, 0, stream>>>(xout, ln5g, ln5b, xn);
  gemmd<1, 512><<<2048, 256, 0, stream>>>(xn, wt_m2w1, m2b1, nullptr, h1,
                                          MQ, 2048, 0, nullptr, 0, 0);
  gemmd<2, 2048><<<512, 256, 0, stream>>>(h1, wt_m2w2, m2b2, xout, xout,
                                          MQ, 512, 0, nullptr, 0, 0);
}